// Round 2
// baseline (581.759 us; speedup 1.0000x reference)
//
#include <hip/hip_runtime.h>
#include <hip/hip_bf16.h>

typedef __attribute__((ext_vector_type(8))) __bf16 bf16x8;
typedef __attribute__((ext_vector_type(8))) unsigned short us8;
typedef __attribute__((ext_vector_type(4))) float f32x4;

typedef long long ll;

// ---------------------------------------------------------------------------
// Unified 128x128-tile GEMM:  C[M,N] = A[M,K] * B[N,K]^T   (both K-major)
// OP 0: proj   A=X fp32, B=Wq/Wk/Wv fp32 (segment by col), C=QKV bf16 (+bias)
// OP 1: scores A=Q bf16, B=K bf16, C=S fp32 (scale 1/32, causal mask -1e30)
// OP 2: PV     A=attn fp32, B=VT bf16, C=out fp32
// ---------------------------------------------------------------------------
template<int OP>
__global__ __launch_bounds__(256) void gemm_bt(
    const void* __restrict__ Ap, const void* __restrict__ B0,
    const void* __restrict__ B1, const void* __restrict__ B2,
    void* __restrict__ Cp,
    const float* __restrict__ bias0, const float* __restrict__ bias1,
    const float* __restrict__ bias2,
    const int* __restrict__ maskp,
    int K, int lda, int ldb, int ldc,
    long long batchA, long long batchB, long long batchC)
{
    constexpr bool A_F32 = (OP == 0) || (OP == 2);
    constexpr bool B_F32 = (OP == 0);

    __shared__ __bf16 lA[128 * 32];
    __shared__ __bf16 lB[128 * 32];

    const int t    = threadIdx.x;
    const int bz   = blockIdx.z;
    const int row0 = blockIdx.x * 128;
    const int col0 = blockIdx.y * 128;

    // B-pointer / bias selection (OP0 concatenates Wq|Wk|Wv along N)
    const void*  Bp    = B0;
    const float* biasp = nullptr;
    int bcol0 = col0;
    if (OP == 0) {
        int seg = col0 >> 10;
        Bp    = (seg == 0) ? B0 : (seg == 1) ? B1 : B2;
        biasp = (seg == 0) ? bias0 : (seg == 1) ? bias1 : bias2;
        bcol0 = col0 & 1023;
    }

    const float*  Af = (const float*)Ap;
    const __bf16* Ah = (const __bf16*)Ap;
    const float*  Bf = (const float*)Bp;
    const __bf16* Bh = (const __bf16*)Bp;

    const long long aoff = (long long)bz * batchA;
    const long long boff = (long long)bz * batchB;
    const long long coff = (long long)bz * batchC;

    f32x4 acc[4][4] = {};

    const int w    = t >> 6;
    const int lane = t & 63;
    const int wr   = (w >> 1) * 64;   // wave row origin in tile
    const int wc   = (w & 1) * 64;    // wave col origin in tile

    const int sr = t >> 1;            // staging row 0..127
    const int sc = (t & 1) * 16;      // staging col 0 or 16

    for (int kt = 0; kt < K; kt += 32) {
        // ---- stage A tile (128 x 32) ----
        {
            long long g = aoff + (long long)(row0 + sr) * lda + kt + sc;
            __bf16* dst = &lA[sr * 32 + sc];
            if (A_F32) {
                const f32x4* p = (const f32x4*)&Af[g];
                f32x4 v0 = p[0], v1 = p[1], v2 = p[2], v3 = p[3];
                bf16x8 h0, h1;
                #pragma unroll
                for (int i = 0; i < 4; ++i) {
                    h0[i]     = (__bf16)v0[i];
                    h0[i + 4] = (__bf16)v1[i];
                    h1[i]     = (__bf16)v2[i];
                    h1[i + 4] = (__bf16)v3[i];
                }
                ((bf16x8*)dst)[0] = h0;
                ((bf16x8*)dst)[1] = h1;
            } else {
                const bf16x8* p = (const bf16x8*)&Ah[g];
                bf16x8 v0 = p[0], v1 = p[1];
                ((bf16x8*)dst)[0] = v0;
                ((bf16x8*)dst)[1] = v1;
            }
        }
        // ---- stage B tile (128 x 32) ----
        {
            long long g = boff + (long long)(bcol0 + sr) * ldb + kt + sc;
            __bf16* dst = &lB[sr * 32 + sc];
            if (B_F32) {
                const f32x4* p = (const f32x4*)&Bf[g];
                f32x4 v0 = p[0], v1 = p[1], v2 = p[2], v3 = p[3];
                bf16x8 h0, h1;
                #pragma unroll
                for (int i = 0; i < 4; ++i) {
                    h0[i]     = (__bf16)v0[i];
                    h0[i + 4] = (__bf16)v1[i];
                    h1[i]     = (__bf16)v2[i];
                    h1[i + 4] = (__bf16)v3[i];
                }
                ((bf16x8*)dst)[0] = h0;
                ((bf16x8*)dst)[1] = h1;
            } else {
                const bf16x8* p = (const bf16x8*)&Bh[g];
                bf16x8 v0 = p[0], v1 = p[1];
                ((bf16x8*)dst)[0] = v0;
                ((bf16x8*)dst)[1] = v1;
            }
        }
        __syncthreads();

        // ---- fragments + MFMA ----
        bf16x8 afr[4], bfr[4];
        const int ko = (lane >> 4) * 8;
        #pragma unroll
        for (int i = 0; i < 4; ++i)
            afr[i] = *(const bf16x8*)&lA[(wr + i * 16 + (lane & 15)) * 32 + ko];
        #pragma unroll
        for (int j = 0; j < 4; ++j)
            bfr[j] = *(const bf16x8*)&lB[(wc + j * 16 + (lane & 15)) * 32 + ko];
        #pragma unroll
        for (int i = 0; i < 4; ++i)
            #pragma unroll
            for (int j = 0; j < 4; ++j)
                acc[i][j] = __builtin_amdgcn_mfma_f32_16x16x32_bf16(
                    afr[i], bfr[j], acc[i][j], 0, 0, 0);
        __syncthreads();
    }

    // ---- epilogue ----
    const int msk = (OP == 1) ? maskp[0] : 0;
    #pragma unroll
    for (int i = 0; i < 4; ++i) {
        #pragma unroll
        for (int j = 0; j < 4; ++j) {
            const int col = col0 + wc + j * 16 + (lane & 15);
            #pragma unroll
            for (int r = 0; r < 4; ++r) {
                const int row = row0 + wr + i * 16 + (lane >> 4) * 4 + r;
                float v = acc[i][j][r];
                if (OP == 0) {
                    v += biasp[col & 1023];
                    ((__bf16*)Cp)[coff + (long long)row * ldc + col] = (__bf16)v;
                } else if (OP == 1) {
                    v *= 0.03125f;                       // 1/sqrt(1024)
                    if (msk && col > row) v = -1e30f;    // causal (strictly upper)
                    ((float*)Cp)[coff + (long long)row * ldc + col] = v;
                } else {
                    ((float*)Cp)[coff + (long long)row * ldc + col] = v;
                }
            }
        }
    }
}

// ---------------------------------------------------------------------------
// V transpose: VT[b][k][m] = V[b][m][k]  (bf16, from QKV cols 2048..3071)
// ---------------------------------------------------------------------------
__global__ __launch_bounds__(256) void vt_k(const unsigned short* __restrict__ qkv,
                                            unsigned short* __restrict__ vt)
{
    __shared__ unsigned short tile[64][72];   // padded rows to break conflicts
    const int t  = threadIdx.x;
    const int m0 = blockIdx.x * 64;
    const int k0 = blockIdx.y * 64;
    const int b  = blockIdx.z;

    const unsigned short* V = qkv + (ll)b * 2048 * 3072 + 2048;
    #pragma unroll
    for (int h = 0; h < 2; ++h) {
        int r = (t >> 3) + h * 32;
        int c = (t & 7) * 8;
        us8 v = *(const us8*)&V[(ll)(m0 + r) * 3072 + k0 + c];
        *(us8*)&tile[r][c] = v;
    }
    __syncthreads();
    unsigned short* O = vt + (ll)b * 1024 * 2048;
    #pragma unroll
    for (int h = 0; h < 2; ++h) {
        int k = (t >> 3) + h * 32;
        int m = (t & 7) * 8;
        us8 o;
        #pragma unroll
        for (int j = 0; j < 8; ++j) o[j] = tile[m + j][k];
        *(us8*)&O[(ll)(k0 + k) * 2048 + m0 + m] = o;
    }
}

// ---------------------------------------------------------------------------
// Column softmax over axis l (per (b, m) column), deterministic two-phase.
// Scores are bounded (|s| ~< 4) so no max subtraction; masked = -1e30 -> 0.
// ---------------------------------------------------------------------------
__global__ __launch_bounds__(256) void colsum_k(const float* __restrict__ S,
                                                float* __restrict__ part)
{
    const int lc = blockIdx.x, mc = blockIdx.y, b = blockIdx.z;
    const int m  = mc * 256 + threadIdx.x;
    const float* p = S + (ll)b * 2048 * 2048 + (ll)(lc * 256) * 2048 + m;
    float s = 0.f;
    #pragma unroll 4
    for (int l = 0; l < 256; ++l) s += __expf(p[(ll)l * 2048]);
    part[((ll)lc * 8 + b) * 2048 + m] = s;
}

__global__ __launch_bounds__(256) void norm_k(float* __restrict__ S,
                                              const float* __restrict__ part)
{
    const int lc = blockIdx.x, mc = blockIdx.y, b = blockIdx.z;
    const int m  = mc * 256 + threadIdx.x;
    float s = 0.f;
    #pragma unroll
    for (int j = 0; j < 8; ++j) s += part[((ll)j * 8 + b) * 2048 + m];
    const float inv = 1.0f / s;
    float* p = S + (ll)b * 2048 * 2048 + (ll)(lc * 256) * 2048 + m;
    #pragma unroll 4
    for (int l = 0; l < 256; ++l) {
        float v = p[(ll)l * 2048];
        p[(ll)l * 2048] = __expf(v) * inv;
    }
}

// ---------------------------------------------------------------------------
extern "C" void kernel_launch(void* const* d_in, const int* in_sizes, int n_in,
                              void* d_out, int out_size, void* d_ws, size_t ws_size,
                              hipStream_t stream)
{
    const float* X   = (const float*)d_in[0];
    const float* Wq  = (const float*)d_in[1];
    const float* bq  = (const float*)d_in[2];
    const float* Wk  = (const float*)d_in[3];
    const float* bk  = (const float*)d_in[4];
    const float* Wv  = (const float*)d_in[5];
    const float* bv  = (const float*)d_in[6];
    const int*   msk = (const int*)d_in[7];

    __bf16* qkv = (__bf16*)d_ws;                      // 16384 x 3072 bf16 (96 MiB)
    __bf16* vt  = qkv + (ll)16384 * 3072;             // 8 x 1024 x 2048 bf16 (32 MiB)
    float*  prt = (float*)(vt + (ll)8 * 1024 * 2048); // 8*8*2048 fp32

    float* out  = (float*)d_out;                      // (8,2048,1024)
    float* attn = out + (ll)8 * 2048 * 1024;          // (8,2048,2048) — also S scratch

    // 1) QKV projection:  QKV[n, 0:3072] = X @ [Wq|Wk|Wv]^T + bias  (bf16 out)
    gemm_bt<0><<<dim3(128, 24, 1), 256, 0, stream>>>(
        X, Wq, Wk, Wv, qkv, bq, bk, bv, nullptr,
        1024, 1024, 1024, 3072, 0LL, 0LL, 0LL);

    // 2) V transpose for PV's B-operand (reduction-contiguous)
    vt_k<<<dim3(32, 16, 8), 256, 0, stream>>>((const unsigned short*)qkv,
                                              (unsigned short*)vt);

    // 3) Scores: S[b] = Q[b] K[b]^T / 32, causal mask -> attn region of d_out
    gemm_bt<1><<<dim3(16, 16, 8), 256, 0, stream>>>(
        qkv, qkv + 1024, nullptr, nullptr, attn,
        nullptr, nullptr, nullptr, msk,
        1024, 3072, 3072, 2048,
        (ll)2048 * 3072, (ll)2048 * 3072, (ll)2048 * 2048);

    // 4) column-sum partials (softmax over axis=1 == per-column over l)
    colsum_k<<<dim3(8, 8, 8), 256, 0, stream>>>(attn, prt);

    // 5) normalize in place: attn = exp(S) / colsum
    norm_k<<<dim3(8, 8, 8), 256, 0, stream>>>(attn, prt);

    // 6) PV: out[b] = attn[b] @ VT[b]^T
    gemm_bt<2><<<dim3(16, 8, 8), 256, 0, stream>>>(
        attn, vt, nullptr, nullptr, out,
        nullptr, nullptr, nullptr, nullptr,
        2048, 2048, 2048, 1024,
        (ll)2048 * 2048, (ll)1024 * 2048, (ll)2048 * 1024);
}

// Round 3
// 488.562 us; speedup vs baseline: 1.1908x; 1.1908x over previous
//
#include <hip/hip_runtime.h>
#include <hip/hip_bf16.h>

typedef __attribute__((ext_vector_type(8))) __bf16 bf16x8;
typedef __attribute__((ext_vector_type(8))) unsigned short us8;
typedef __attribute__((ext_vector_type(4))) float f32x4;
typedef long long ll;

// async global->LDS, 16B per lane, dst = wave-uniform base + lane*16
#define GLD(gp, lp) __builtin_amdgcn_global_load_lds( \
    (const __attribute__((address_space(1))) void*)(gp), \
    (__attribute__((address_space(3))) void*)(lp), 16, 0, 0)

// ---------------------------------------------------------------------------
// m97-style 128x128 GEMM, BK=32:  C[M,N] = A[M,K] * B[N,K]^T  (bf16 inputs)
// OP 0: proj   C = bf16 (A=Xb, B=Wb concat, +bias concat)
// OP 1: scores C = fp32 E = exp(v/32, causal-masked -> 0)
// OP 2: PV     C = fp32 out
// ---------------------------------------------------------------------------
template<int OP>
__global__ __launch_bounds__(256) void gemm_bt(
    const __bf16* __restrict__ A, const __bf16* __restrict__ B,
    void* __restrict__ Cp, const float* __restrict__ bias,
    const int* __restrict__ maskp,
    int K, int lda, int ldb, int ldc,
    ll batchA, ll batchB, ll batchC)
{
    __shared__ __bf16 lA[128 * 32];
    __shared__ __bf16 lB[128 * 32];

    const int t    = threadIdx.x;
    const int w    = t >> 6;
    const int lane = t & 63;
    const int bz   = blockIdx.z;
    const int row0 = blockIdx.x * 128;
    const int col0 = blockIdx.y * 128;

    const __bf16* Ab = A + (ll)bz * batchA;
    const __bf16* Bb = B + (ll)bz * batchB;

    const int srow = lane >> 2;        // 0..15 (row within 16-row issue)
    const int scol = (lane & 3) * 8;   // bf16 elem offset (16B per lane)

    f32x4 acc[4][4] = {};
    const int wr = (w >> 1) * 64;
    const int wc = (w & 1) * 64;
    const int fr = lane & 15;
    const int ko = (lane >> 4) * 8;

    for (int kt = 0; kt < K; kt += 32) {
        // wave w stages rows [w*32, w*32+32) of both tiles (2 issues x 16 rows)
        #pragma unroll
        for (int is = 0; is < 2; ++is) {
            const int r = w * 32 + is * 16 + srow;
            GLD(Ab + (ll)(row0 + r) * lda + kt + scol, &lA[(w * 32 + is * 16) * 32]);
            GLD(Bb + (ll)(col0 + r) * ldb + kt + scol, &lB[(w * 32 + is * 16) * 32]);
        }
        __syncthreads();

        bf16x8 afr[4], bfr[4];
        #pragma unroll
        for (int i = 0; i < 4; ++i)
            afr[i] = *(const bf16x8*)&lA[(wr + i * 16 + fr) * 32 + ko];
        #pragma unroll
        for (int j = 0; j < 4; ++j)
            bfr[j] = *(const bf16x8*)&lB[(wc + j * 16 + fr) * 32 + ko];
        #pragma unroll
        for (int i = 0; i < 4; ++i)
            #pragma unroll
            for (int j = 0; j < 4; ++j)
                acc[i][j] = __builtin_amdgcn_mfma_f32_16x16x32_bf16(
                    afr[i], bfr[j], acc[i][j], 0, 0, 0);
        __syncthreads();
    }

    const ll coff = (ll)bz * batchC;
    const int msk = (OP == 1) ? maskp[0] : 0;
    #pragma unroll
    for (int i = 0; i < 4; ++i) {
        #pragma unroll
        for (int j = 0; j < 4; ++j) {
            const int col = col0 + wc + j * 16 + fr;
            #pragma unroll
            for (int r4 = 0; r4 < 4; ++r4) {
                const int row = row0 + wr + i * 16 + (lane >> 4) * 4 + r4;
                float v = acc[i][j][r4];
                if (OP == 0) {
                    v += bias[col];
                    ((__bf16*)Cp)[coff + (ll)row * ldc + col] = (__bf16)v;
                } else if (OP == 1) {
                    float e = (msk && col > row) ? 0.f : __expf(v * 0.03125f);
                    ((float*)Cp)[coff + (ll)row * ldc + col] = e;
                } else {
                    ((float*)Cp)[coff + (ll)row * ldc + col] = v;
                }
            }
        }
    }
}

// ---------------------------------------------------------------------------
// fp32 -> bf16 bulk convert (8 elems/thread)
// ---------------------------------------------------------------------------
__global__ __launch_bounds__(256) void cvt_k(const float* __restrict__ in,
                                             __bf16* __restrict__ out, int n8)
{
    const int i = blockIdx.x * 256 + threadIdx.x;
    if (i >= n8) return;
    const f32x4* p = (const f32x4*)(in + (ll)i * 8);
    f32x4 a = p[0], b = p[1];
    bf16x8 h;
    #pragma unroll
    for (int j = 0; j < 4; ++j) { h[j] = (__bf16)a[j]; h[j + 4] = (__bf16)b[j]; }
    *(bf16x8*)(out + (ll)i * 8) = h;
}

__global__ __launch_bounds__(256) void cvtb_k(const float* __restrict__ q,
                                              const float* __restrict__ k,
                                              const float* __restrict__ v,
                                              float* __restrict__ bb)
{
    const int i = blockIdx.x * 256 + threadIdx.x;   // 0..3071
    bb[i] = (i < 1024) ? q[i] : (i < 2048) ? k[i - 1024] : v[i - 2048];
}

// ---------------------------------------------------------------------------
// V transpose: VT[b][k][m] = V[b][m][k]  (bf16, from QKV cols 2048..3071)
// ---------------------------------------------------------------------------
__global__ __launch_bounds__(256) void vt_k(const unsigned short* __restrict__ qkv,
                                            unsigned short* __restrict__ vt)
{
    __shared__ unsigned short tile[64][72];
    const int t  = threadIdx.x;
    const int m0 = blockIdx.x * 64;
    const int k0 = blockIdx.y * 64;
    const int b  = blockIdx.z;

    const unsigned short* V = qkv + (ll)b * 2048 * 3072 + 2048;
    #pragma unroll
    for (int h = 0; h < 2; ++h) {
        int r = (t >> 3) + h * 32;
        int c = (t & 7) * 8;
        us8 v = *(const us8*)&V[(ll)(m0 + r) * 3072 + k0 + c];
        *(us8*)&tile[r][c] = v;
    }
    __syncthreads();
    unsigned short* O = vt + (ll)b * 1024 * 2048;
    #pragma unroll
    for (int h = 0; h < 2; ++h) {
        int k = (t >> 3) + h * 32;
        int m = (t & 7) * 8;
        us8 o;
        #pragma unroll
        for (int j = 0; j < 8; ++j) o[j] = tile[m + j][k];
        *(us8*)&O[(ll)(k0 + k) * 2048 + m0 + m] = o;
    }
}

// ---------------------------------------------------------------------------
// Column softmax over l (per (b,m)), two-phase deterministic. E pre-expd.
// ---------------------------------------------------------------------------
__global__ __launch_bounds__(256) void colsum_k(const float* __restrict__ E,
                                                float* __restrict__ part)
{
    const int lc = blockIdx.x, mc = blockIdx.y, b = blockIdx.z;
    const int m  = mc * 256 + threadIdx.x;
    const float* p = E + (ll)b * 2048 * 2048 + (ll)(lc * 256) * 2048 + m;
    float s = 0.f;
    #pragma unroll 4
    for (int l = 0; l < 256; ++l) s += p[(ll)l * 2048];
    part[((ll)lc * 8 + b) * 2048 + m] = s;
}

__global__ __launch_bounds__(256) void norm_k(float* __restrict__ E,
                                              const float* __restrict__ part,
                                              __bf16* __restrict__ attn_bf)
{
    const int lc = blockIdx.x, mc = blockIdx.y, b = blockIdx.z;
    const int m  = mc * 256 + threadIdx.x;
    float s = 0.f;
    #pragma unroll
    for (int j = 0; j < 8; ++j) s += part[((ll)j * 8 + b) * 2048 + m];
    const float inv = 1.0f / s;
    float* p = E + (ll)b * 2048 * 2048 + (ll)(lc * 256) * 2048 + m;
    __bf16* q = attn_bf + (ll)b * 2048 * 2048 + (ll)(lc * 256) * 2048 + m;
    #pragma unroll 4
    for (int l = 0; l < 256; ++l) {
        float a = p[(ll)l * 2048] * inv;
        p[(ll)l * 2048] = a;
        q[(ll)l * 2048] = (__bf16)a;
    }
}

// ---------------------------------------------------------------------------
extern "C" void kernel_launch(void* const* d_in, const int* in_sizes, int n_in,
                              void* d_out, int out_size, void* d_ws, size_t ws_size,
                              hipStream_t stream)
{
    const float* X   = (const float*)d_in[0];
    const float* Wq  = (const float*)d_in[1];
    const float* bq  = (const float*)d_in[2];
    const float* Wk  = (const float*)d_in[3];
    const float* bk  = (const float*)d_in[4];
    const float* Wv  = (const float*)d_in[5];
    const float* bv  = (const float*)d_in[6];
    const int*   msk = (const int*)d_in[7];

    float* out  = (float*)d_out;                  // (8,2048,1024) fp32
    float* attn = out + (ll)8 * 2048 * 1024;      // (8,2048,2048) fp32 (also E)

    // transient bf16 staging inside the (not-yet-written) attn region
    __bf16* Xb = (__bf16*)attn;                   // 16384 x 1024 (32 MiB)
    __bf16* Wb = Xb + (ll)16384 * 1024;           // 3072 x 1024  (6 MiB)
    float*  bb = (float*)(Wb + (ll)3072 * 1024);  // 3072 fp32

    __bf16* qkv = (__bf16*)d_ws;                  // 16384 x 3072 (96 MiB)
    __bf16* vt  = qkv + (ll)16384 * 3072;         // 8 x 1024 x 2048 (32 MiB)
    float*  prt = (float*)(vt + (ll)8 * 1024 * 2048);
    __bf16* attn_bf = qkv;                        // aliases qkv (dead by then)

    // 0) bf16 conversions
    cvt_k<<<dim3(8192), 256, 0, stream>>>(X, Xb, 16384 * 1024 / 8);
    cvt_k<<<dim3(512),  256, 0, stream>>>(Wq, Wb,               1024 * 1024 / 8);
    cvt_k<<<dim3(512),  256, 0, stream>>>(Wk, Wb + 1024 * 1024, 1024 * 1024 / 8);
    cvt_k<<<dim3(512),  256, 0, stream>>>(Wv, Wb + 2048 * 1024, 1024 * 1024 / 8);
    cvtb_k<<<dim3(12),  256, 0, stream>>>(bq, bk, bv, bb);

    // 1) QKV projection: qkv = Xb @ Wb^T + bb   (bf16 out)
    gemm_bt<0><<<dim3(128, 24, 1), 256, 0, stream>>>(
        Xb, Wb, qkv, bb, nullptr,
        1024, 1024, 1024, 3072, 0LL, 0LL, 0LL);

    // 2) V transpose for PV's B-operand
    vt_k<<<dim3(32, 16, 8), 256, 0, stream>>>((const unsigned short*)qkv,
                                              (unsigned short*)vt);

    // 3) E = exp(Q K^T / 32, masked) -> attn region (overwrites Xb/Wb, now dead)
    gemm_bt<1><<<dim3(16, 16, 8), 256, 0, stream>>>(
        qkv, qkv + 1024, attn, nullptr, msk,
        1024, 3072, 3072, 2048,
        (ll)2048 * 3072, (ll)2048 * 3072, (ll)2048 * 2048);

    // 4) column sums of E (softmax axis=1)
    colsum_k<<<dim3(8, 8, 8), 256, 0, stream>>>(attn, prt);

    // 5) attn = E / colsum (fp32 in place) + bf16 copy over dead qkv
    norm_k<<<dim3(8, 8, 8), 256, 0, stream>>>(attn, prt, attn_bf);

    // 6) out = attn_bf @ vt^T
    gemm_bt<2><<<dim3(16, 8, 8), 256, 0, stream>>>(
        attn_bf, vt, out, nullptr, nullptr,
        2048, 2048, 2048, 1024,
        (ll)2048 * 2048, (ll)1024 * 2048, (ll)2048 * 1024);
}

// Round 4
// 391.796 us; speedup vs baseline: 1.4849x; 1.2470x over previous
//
#include <hip/hip_runtime.h>
#include <hip/hip_bf16.h>

typedef __attribute__((ext_vector_type(8))) __bf16 bf16x8;
typedef __attribute__((ext_vector_type(8))) unsigned short us8;
typedef __attribute__((ext_vector_type(4))) float f32x4;
typedef long long ll;

#define GLD(gp, lp) __builtin_amdgcn_global_load_lds( \
    (const __attribute__((address_space(1))) void*)(gp), \
    (__attribute__((address_space(3))) void*)(lp), 16, 0, 0)

#define SBAR()  asm volatile("s_barrier" ::: "memory")
#define VMCNT4  asm volatile("s_waitcnt vmcnt(4)" ::: "memory")
#define VMCNT0  asm volatile("s_waitcnt vmcnt(0)" ::: "memory")
#define SCHED0() __builtin_amdgcn_sched_barrier(0)

// ---------------------------------------------------------------------------
// 256x256-tile 8-phase GEMM (HK-style schedule, plain HIP).
//   C[M,N] = A[M,K] * B[N,K]^T, bf16 inputs, 512 threads = 8 waves (2M x 4N).
//   BK=64, LDS double-buffered per K-tile, 2 K-tiles per iteration.
//   Stage order: ph1-2 A(2i+1)->slot1 | ph3-4 B(2i+2)->slot0 |
//                ph5-6 A(2i+2)->slot0 | ph7-8 B(2i+3)->slot1.
//   vmcnt(4) at ph4 (slot1 ready for ph5) and ph8 (slot0 ready for next ph1).
//   T2: XOR swizzle via pre-swizzled global source granule + swizzled ds_read.
// OP 0: proj   C = bf16 (+bias)      OP 1: scores C = bf16 exp(v/32, masked)
// OP 2: PV     C = fp32 (K truncated to row0+256 when masked)
// ---------------------------------------------------------------------------
template<int OP>
__global__ __launch_bounds__(512) void gemm8(
    const __bf16* __restrict__ A, const __bf16* __restrict__ B,
    void* __restrict__ Cp, const float* __restrict__ bias,
    const int* __restrict__ maskp,
    int K, int lda, int ldb, int ldc,
    ll batchA, ll batchB, ll batchC)
{
    __shared__ __bf16 LA[2][256][64];
    __shared__ __bf16 LB[2][256][64];

    const int t    = threadIdx.x;
    const int w    = t >> 6, lane = t & 63;
    const int wrm  = w >> 2, wcn  = w & 3;      // 2 x 4 wave grid
    const int fr   = lane & 15, fq = lane >> 4; // fragment row sel / k-granule
    const int bz   = blockIdx.z;
    const int row0 = blockIdx.x * 256;
    const int col0 = blockIdx.y * 256;
    const int msk  = (OP >= 1) ? maskp[0] : 0;

    // scores: fully-masked tile -> write zeros, skip compute
    if (OP == 1 && msk && (int)blockIdx.y > (int)blockIdx.x) {
        __bf16* C = (__bf16*)Cp + (ll)bz * batchC;
        bf16x8 z = {};
        #pragma unroll 4
        for (int pass = 0; pass < 16; ++pass) {
            int r = pass * 16 + (t >> 5);
            *(bf16x8*)&C[(ll)(row0 + r) * ldc + col0 + (t & 31) * 8] = z;
        }
        return;
    }

    int NT = K / 64;                         // K-tiles (even, >= 4)
    if (OP == 2 && msk) NT = (row0 + 256) / 64;
    const int NI = NT / 2;

    const __bf16* Ab = A + (ll)bz * batchA;
    const __bf16* Bb = B + (ll)bz * batchB;

    const int srow = lane >> 3;              // 0..7 row within wave chunk
    const int cg   = (lane & 7) ^ srow;      // pre-swizzled source granule

    auto stageA = [&](int kt, int h, int slot) {
        #pragma unroll
        for (int is = 0; is < 2; ++is)
            GLD(Ab + (ll)(row0 + h*128 + is*64 + w*8 + srow) * lda + kt*64 + cg*8,
                &LA[slot][h*128 + is*64 + w*8][0]);
    };
    auto stageB = [&](int kt, int h, int slot) {
        #pragma unroll
        for (int is = 0; is < 2; ++is)
            GLD(Bb + (ll)(col0 + h*128 + is*64 + w*8 + srow) * ldb + kt*64 + cg*8,
                &LB[slot][h*128 + is*64 + w*8][0]);
    };
    auto rdA = [&](int slot, int row, int g) -> bf16x8 {
        return *(const bf16x8*)&LA[slot][row][(g ^ (row & 7)) << 3];
    };
    auto rdB = [&](int slot, int row, int g) -> bf16x8 {
        return *(const bf16x8*)&LB[slot][row][(g ^ (row & 7)) << 3];
    };

    f32x4  acc[8][4] = {};
    bf16x8 bB[4][2];

    // prologue: K-tile0 (A+B) -> slot0, B of K-tile1 -> slot1
    stageA(0, 0, 0); stageA(0, 1, 0);
    stageB(0, 0, 0); stageB(0, 1, 0);
    stageB(1, 0, 1); stageB(1, 1, 1);
    VMCNT4;                                  // K-tile0 landed; B(1) in flight
    SBAR();

#define PHASE(SLOT, Q, STG, VMC) \
  { \
    if (Q == 0) { \
      _Pragma("unroll") for (int j = 0; j < 4; ++j) \
      _Pragma("unroll") for (int ks = 0; ks < 2; ++ks) \
        bB[j][ks] = rdB(SLOT, wcn*64 + j*16 + fr, ks*4 + fq); \
    } \
    bf16x8 bA[2][2]; \
    _Pragma("unroll") for (int fi = 0; fi < 2; ++fi) \
    _Pragma("unroll") for (int ks = 0; ks < 2; ++ks) \
      bA[fi][ks] = rdA(SLOT, wrm*128 + (Q*2+fi)*16 + fr, ks*4 + fq); \
    STG; \
    VMC; \
    SBAR(); SCHED0(); \
    __builtin_amdgcn_s_setprio(1); \
    _Pragma("unroll") for (int fi = 0; fi < 2; ++fi) \
    _Pragma("unroll") for (int j = 0; j < 4; ++j) \
    _Pragma("unroll") for (int ks = 0; ks < 2; ++ks) \
      acc[Q*2+fi][j] = __builtin_amdgcn_mfma_f32_16x16x32_bf16( \
          bA[fi][ks], bB[j][ks], acc[Q*2+fi][j], 0, 0, 0); \
    __builtin_amdgcn_s_setprio(0); \
    SCHED0(); SBAR(); \
  }

    for (int i = 0; i < NI; ++i) {
        const bool nl = (i < NI - 1);
        const int k1 = 2*i + 1, k2 = 2*i + 2, k3 = 2*i + 3;
        PHASE(0, 0, stageA(k1, 0, 1), );
        PHASE(0, 1, stageA(k1, 1, 1), );
        PHASE(0, 2, if (nl) stageB(k2, 0, 0), );
        PHASE(0, 3, if (nl) stageB(k2, 1, 0), if (nl) { VMCNT4; } else { VMCNT0; });
        PHASE(1, 0, if (nl) stageA(k2, 0, 0), );
        PHASE(1, 1, if (nl) stageA(k2, 1, 0), );
        PHASE(1, 2, if (nl) stageB(k3, 0, 1), );
        PHASE(1, 3, if (nl) stageB(k3, 1, 1), if (nl) { VMCNT4; });
    }
#undef PHASE

    // epilogue
    const ll coff = (ll)bz * batchC;
    #pragma unroll
    for (int fi = 0; fi < 8; ++fi)
    #pragma unroll
    for (int j = 0; j < 4; ++j)
    #pragma unroll
    for (int r4 = 0; r4 < 4; ++r4) {
        const int row = row0 + wrm*128 + fi*16 + fq*4 + r4;
        const int col = col0 + wcn*64 + j*16 + fr;
        float v = acc[fi][j][r4];
        if (OP == 0) {
            v += bias[col];
            ((__bf16*)Cp)[coff + (ll)row * ldc + col] = (__bf16)v;
        } else if (OP == 1) {
            float e = (msk && col > row) ? 0.f : __expf(v * 0.03125f);
            ((__bf16*)Cp)[coff + (ll)row * ldc + col] = (__bf16)e;
        } else {
            ((float*)Cp)[coff + (ll)row * ldc + col] = v;
        }
    }
}

// ---------------------------------------------------------------------------
// fp32 -> bf16 bulk convert (8 elems/thread)
// ---------------------------------------------------------------------------
__global__ __launch_bounds__(256) void cvt_k(const float* __restrict__ in,
                                             __bf16* __restrict__ out, int n8)
{
    const int i = blockIdx.x * 256 + threadIdx.x;
    if (i >= n8) return;
    const f32x4* p = (const f32x4*)(in + (ll)i * 8);
    f32x4 a = p[0], b = p[1];
    bf16x8 h;
    #pragma unroll
    for (int j = 0; j < 4; ++j) { h[j] = (__bf16)a[j]; h[j + 4] = (__bf16)b[j]; }
    *(bf16x8*)(out + (ll)i * 8) = h;
}

__global__ __launch_bounds__(256) void cvtb_k(const float* __restrict__ q,
                                              const float* __restrict__ k,
                                              const float* __restrict__ v,
                                              float* __restrict__ bb)
{
    const int i = blockIdx.x * 256 + threadIdx.x;   // 0..3071
    bb[i] = (i < 1024) ? q[i] : (i < 2048) ? k[i - 1024] : v[i - 2048];
}

// ---------------------------------------------------------------------------
// V transpose: VT[b][k][m] = V[b][m][k]  (bf16, from QKV cols 2048..3071)
// ---------------------------------------------------------------------------
__global__ __launch_bounds__(256) void vt_k(const unsigned short* __restrict__ qkv,
                                            unsigned short* __restrict__ vt)
{
    __shared__ unsigned short tile[64][72];
    const int t  = threadIdx.x;
    const int m0 = blockIdx.x * 64;
    const int k0 = blockIdx.y * 64;
    const int b  = blockIdx.z;

    const unsigned short* V = qkv + (ll)b * 2048 * 3072 + 2048;
    #pragma unroll
    for (int h = 0; h < 2; ++h) {
        int r = (t >> 3) + h * 32;
        int c = (t & 7) * 8;
        us8 v = *(const us8*)&V[(ll)(m0 + r) * 3072 + k0 + c];
        *(us8*)&tile[r][c] = v;
    }
    __syncthreads();
    unsigned short* O = vt + (ll)b * 1024 * 2048;
    #pragma unroll
    for (int h = 0; h < 2; ++h) {
        int k = (t >> 3) + h * 32;
        int m = (t & 7) * 8;
        us8 o;
        #pragma unroll
        for (int j = 0; j < 8; ++j) o[j] = tile[m + j][k];
        *(us8*)&O[(ll)(k0 + k) * 2048 + m0 + m] = o;
    }
}

// ---------------------------------------------------------------------------
// Column softmax over l (per (b,m)), two-phase deterministic. E is bf16.
// ---------------------------------------------------------------------------
__global__ __launch_bounds__(256) void colsum_k(const __bf16* __restrict__ E,
                                                float* __restrict__ part)
{
    const int lc = blockIdx.x, mc = blockIdx.y, b = blockIdx.z;
    const int m  = mc * 256 + threadIdx.x;
    const __bf16* p = E + (ll)b * 2048 * 2048 + (ll)(lc * 256) * 2048 + m;
    float s = 0.f;
    #pragma unroll 4
    for (int l = 0; l < 256; ++l) s += (float)p[(ll)l * 2048];
    part[((ll)lc * 8 + b) * 2048 + m] = s;
}

__global__ __launch_bounds__(256) void norm_k(const __bf16* __restrict__ E,
                                              const float* __restrict__ part,
                                              float* __restrict__ attn,
                                              __bf16* __restrict__ attn_bf)
{
    const int lc = blockIdx.x, mc = blockIdx.y, b = blockIdx.z;
    const int m  = mc * 256 + threadIdx.x;
    float s = 0.f;
    #pragma unroll
    for (int j = 0; j < 8; ++j) s += part[((ll)j * 8 + b) * 2048 + m];
    const float inv = 1.0f / s;
    const __bf16* p = E + (ll)b * 2048 * 2048 + (ll)(lc * 256) * 2048 + m;
    float*  qo = attn    + (ll)b * 2048 * 2048 + (ll)(lc * 256) * 2048 + m;
    __bf16* ro = attn_bf + (ll)b * 2048 * 2048 + (ll)(lc * 256) * 2048 + m;
    #pragma unroll 4
    for (int l = 0; l < 256; ++l) {
        float a = (float)p[(ll)l * 2048] * inv;
        qo[(ll)l * 2048] = a;
        ro[(ll)l * 2048] = (__bf16)a;
    }
}

// ---------------------------------------------------------------------------
extern "C" void kernel_launch(void* const* d_in, const int* in_sizes, int n_in,
                              void* d_out, int out_size, void* d_ws, size_t ws_size,
                              hipStream_t stream)
{
    const float* X   = (const float*)d_in[0];
    const float* Wq  = (const float*)d_in[1];
    const float* bq  = (const float*)d_in[2];
    const float* Wk  = (const float*)d_in[3];
    const float* bk  = (const float*)d_in[4];
    const float* Wv  = (const float*)d_in[5];
    const float* bv  = (const float*)d_in[6];
    const int*   msk = (const int*)d_in[7];

    float* out  = (float*)d_out;                  // (8,2048,1024) fp32
    float* attn = out + (ll)8 * 2048 * 1024;      // (8,2048,2048) fp32

    // E (bf16) lives in the out region (dead until PV); exactly 64 MiB
    __bf16* E = (__bf16*)d_out;

    // transient bf16 staging in the attn region (dead until norm)
    __bf16* Xb = (__bf16*)attn;                   // 16384 x 1024 (32 MiB)
    __bf16* Wb = Xb + (ll)16384 * 1024;           // 3072 x 1024  (6 MiB)
    float*  bb = (float*)(Wb + (ll)3072 * 1024);  // 3072 fp32

    __bf16* qkv = (__bf16*)d_ws;                  // 16384 x 3072 (96 MiB)
    __bf16* vt  = qkv + (ll)16384 * 3072;         // 8 x 1024 x 2048 (32 MiB)
    float*  prt = (float*)(vt + (ll)8 * 1024 * 2048);
    __bf16* attn_bf = qkv;                        // reuse qkv (dead after scores+vt)

    // 0) bf16 conversions
    cvt_k<<<dim3(8192), 256, 0, stream>>>(X, Xb, 16384 * 1024 / 8);
    cvt_k<<<dim3(512),  256, 0, stream>>>(Wq, Wb,               1024 * 1024 / 8);
    cvt_k<<<dim3(512),  256, 0, stream>>>(Wk, Wb + 1024 * 1024, 1024 * 1024 / 8);
    cvt_k<<<dim3(512),  256, 0, stream>>>(Wv, Wb + 2048 * 1024, 1024 * 1024 / 8);
    cvtb_k<<<dim3(12),  256, 0, stream>>>(bq, bk, bv, bb);

    // 1) QKV projection: qkv = Xb @ Wb^T + bb (bf16)
    gemm8<0><<<dim3(64, 12, 1), 512, 0, stream>>>(
        Xb, Wb, qkv, bb, msk,
        1024, 1024, 1024, 3072, 0LL, 0LL, 0LL);

    // 2) V transpose
    vt_k<<<dim3(32, 16, 8), 256, 0, stream>>>((const unsigned short*)qkv,
                                              (unsigned short*)vt);

    // 3) E = exp(Q K^T / 32, masked) as bf16 -> out region (overwrites nothing live)
    gemm8<1><<<dim3(8, 8, 8), 512, 0, stream>>>(
        qkv, qkv + 1024, E, nullptr, msk,
        1024, 3072, 3072, 2048,
        (ll)2048 * 3072, (ll)2048 * 3072, (ll)2048 * 2048);

    // 4) column sums of E (softmax axis=1)
    colsum_k<<<dim3(8, 8, 8), 256, 0, stream>>>(E, prt);

    // 5) attn = E/colsum: fp32 -> d_out attn region, bf16 -> attn_bf (over qkv)
    norm_k<<<dim3(8, 8, 8), 256, 0, stream>>>(E, prt, attn, attn_bf);

    // 6) out = attn_bf @ vt^T (overwrites E region; E dead). K truncated by mask.
    gemm8<2><<<dim3(8, 4, 8), 512, 0, stream>>>(
        attn_bf, vt, out, nullptr, msk,
        2048, 2048, 2048, 1024,
        (ll)2048 * 2048, (ll)1024 * 2048, (ll)2048 * 1024);
}